// Round 4
// baseline (844.097 us; speedup 1.0000x reference)
//
#include <hip/hip_runtime.h>
#include <cstdint>
#include <cstddef>

typedef unsigned int u32;
typedef unsigned short u16;
typedef unsigned long long u64;

#define NUM_EL 2359296
#define N_ROWS 294912
#define N_OPS  262144
#define OFF1   1048576
#define OFF2   2097152

// ---------------- workspace layout (bytes) ----------------
// addr:    [0, 9437184)            u32[NUM_EL]
// featsM:  [18874368, 56623104)    bf16[NUM_EL*8] memory-position order (37.75MB)
//          sort1 scratch overlays (dead before k_conv):
//    kA=+0, kB=+9437184, v0=+18874368, v1=+28311552
// counts0: [56623104, 56918016)    u32[256*288]
// pos:     [57507840, 57802752)    u32[256*288]
// part:    [57802752, 60162048)    float[64*9216]
// flat:    [60162048, 60163072)    float[256]
// wt:      [60163072, 60167680)    float[1152]
// pgp:     [60167680, 60168192)    double[64] (only [0],[1] used: penalty atomics)
// bar:     [60168192, 60168256)    u32 ticket counter
// ops:     [60168256, 64362560)    float4[N_OPS]
// k2A/k2B/v2A/v2B: [64362560, +4MB)
#define OFF_F8     18874368ull
#define OFF_C0     56623104ull
#define OFF_POS    57507840ull
#define OFF_PART   57802752ull
#define OFF_FLAT   60162048ull
#define OFF_WT     60163072ull
#define OFF_PGP    60167680ull
#define OFF_BAR    60168192ull
#define OFF_OPS    60168256ull
#define OFF_S2     64362560ull

__device__ inline u32 pk_bf16(float a, float b) {  // RNE pack of 2 floats -> 2 bf16
  u32 ua = __float_as_uint(a), ub = __float_as_uint(b);
  ua = (ua + 0x7fffu + ((ua >> 16) & 1u)) >> 16;
  ub = (ub + 0x7fffu + ((ub >> 16) & 1u)) >> 16;
  return ua | (ub << 16);
}

// front: sort1 keys + fused pass-0 histogram (blocks 0..287, LDS atomics only),
// weight transpose + penalty-accumulator/ticket zero (block 288).
__global__ __launch_bounds__(256) void k_front(const float* __restrict__ x,
                                               u32* __restrict__ keys,
                                               u32* __restrict__ counts0,
                                               const float* __restrict__ mw, float* __restrict__ wt,
                                               u32* __restrict__ bar, double* __restrict__ pgp) {
  int b = blockIdx.x, t = threadIdx.x;
  if (b < 288) {
    __shared__ u32 h[256];
    h[t] = 0u;
    __syncthreads();
    int base = b * 8192;
#pragma unroll
    for (int k = 0; k < 32; k++) {
      int i = base + k * 256 + t;
      u32 u = __float_as_uint(x[i]);
      u = (u & 0x80000000u) ? ~u : (u | 0x80000000u);
      keys[i] = u;
      atomicAdd(&h[(u >> 8) & 255u], 1u);
    }
    __syncthreads();
    counts0[t * 288 + b] = h[t];  // digit-major
  } else {
    for (int i = t; i < 1152; i += 256) {
      int oc = i & 15;
      int rest = i >> 4;
      int ic = rest & 7;
      int p = rest >> 3;
      int dr = p / 3, dl = p % 3;
      wt[i] = mw[((oc * 8 + ic) * 3 + dr) * 3 + dl];
    }
    if (t == 0) { bar[0] = 0u; pgp[0] = 0.0; pgp[1] = 0.0; }
  }
}

// 512 threads, 8192-elem tile, 16 keys/thread. LDS histogram, coalesced output.
__global__ __launch_bounds__(512) void k_hist(const u32* __restrict__ keys,
                                              u32* __restrict__ counts, int shift, int nB) {
  __shared__ u32 h[256];
  int t = threadIdx.x;
  if (t < 256) h[t] = 0;
  __syncthreads();
  int base = blockIdx.x * 8192;
#pragma unroll
  for (int k = 0; k < 16; k++) {
    u32 d = (keys[base + t + k * 512] >> shift) & 255u;
    atomicAdd(&h[d], 1u);
  }
  __syncthreads();
  if (t < 256) counts[t * nB + blockIdx.x] = h[t];  // digit-major
}

// 256 blocks (one per digit): base = sum counts[0, d*nB), then row scan in LDS.
__global__ __launch_bounds__(256) void k_scan_par(const u32* __restrict__ counts,
                                                  u32* __restrict__ pos, int nB) {
  int d = blockIdx.x, t = threadIdx.x;
  __shared__ u32 red[256];
  u32 s = 0;
  u32 lim = (u32)(d * nB);
  for (u32 i = t; i < lim; i += 256) s += counts[i];
  red[t] = s;
  __syncthreads();
  for (int off = 128; off > 0; off >>= 1) {
    if (t < off) red[t] += red[t + off];
    __syncthreads();
  }
  u32 base = red[0];
  __syncthreads();
  int chunk = (nB + 255) / 256;
  int i0 = t * chunk;
  u32 loc[4];
  u32 lsum = 0;
#pragma unroll 4
  for (int k = 0; k < chunk; k++) {
    int i = i0 + k;
    u32 v = (i < nB) ? counts[d * nB + i] : 0u;
    loc[k] = lsum;
    lsum += v;
  }
  red[t] = lsum;
  __syncthreads();
  for (int off = 1; off < 256; off <<= 1) {
    u32 y = (t >= off) ? red[t - off] : 0u;
    __syncthreads();
    red[t] += y;
    __syncthreads();
  }
  u32 excl = red[t] - lsum;
#pragma unroll 4
  for (int k = 0; k < chunk; k++) {
    int i = i0 + k;
    if (i < nB) pos[d * nB + i] = base + excl + loc[k];
  }
}

// Stable scatter, 8192 tile, LDS reorder-by-digit -> coalesced global runs.
// gen_iota: vals = global index (pass 0, vin unused).
// mode: 0 = write keys+vals; 1 = write vals only (final pass).
__global__ __launch_bounds__(512) void k_scatter(const u32* __restrict__ kin, const u32* __restrict__ vin,
                                                 u32* __restrict__ kout, u32* __restrict__ vout,
                                                 const u32* __restrict__ gbase, int shift, int nB,
                                                 int gen_iota, int mode) {
  __shared__ u32 sk[8192], sv[8192];
  __shared__ u32 whist[8][256];
  __shared__ u32 sbase[256], lstart[256], gdelta[256], red[256];
  int t = threadIdx.x, b = blockIdx.x;
  int base = b * 8192;
  if (t < 256) {
#pragma unroll
    for (int w2 = 0; w2 < 8; w2++) whist[w2][t] = 0;
    sbase[t] = gbase[t * nB + b];
  }
  __syncthreads();
  int w = t >> 6, lane = t & 63;
  u64 lowmask = (1ull << lane) - 1ull;
  u32 kk[16], vv[16], dig[16], rnk[16];
#pragma unroll
  for (int j = 0; j < 16; j++) {
    int idx = base + w * 1024 + j * 64 + lane;
    kk[j] = kin[idx];
    vv[j] = gen_iota ? (u32)idx : vin[idx];
  }
#pragma unroll
  for (int j = 0; j < 16; j++) {
    u32 d = (kk[j] >> shift) & 255u;
    u64 m = ~0ull;
#pragma unroll
    for (int bit = 0; bit < 8; bit++) {
      u64 bal = __ballot((d >> bit) & 1u);
      m &= ((d >> bit) & 1u) ? bal : ~bal;
    }
    u32 rr = (u32)__popcll(m & lowmask);
    u32 cnt = (u32)__popcll(m);
    u32 prev = whist[w][d];        // wave-synchronous LDS read
    if (rr == 0) whist[w][d] = prev + cnt;
    dig[j] = d;
    rnk[j] = prev + rr;
  }
  __syncthreads();
  u32 tot = 0;
  if (t < 256) {
    u32 sacc = 0;
#pragma unroll
    for (int ww = 0; ww < 8; ww++) { u32 v = whist[ww][t]; whist[ww][t] = sacc; sacc += v; }
    tot = sacc;
    red[t] = tot;
  }
  __syncthreads();
  for (int off = 1; off < 256; off <<= 1) {
    u32 y = (t < 256 && t >= off) ? red[t - off] : 0u;
    __syncthreads();
    if (t < 256) red[t] += y;
    __syncthreads();
  }
  if (t < 256) {
    u32 lst = red[t] - tot;
    lstart[t] = lst;
    gdelta[t] = sbase[t] - lst;
  }
  __syncthreads();
#pragma unroll
  for (int j = 0; j < 16; j++) {
    u32 d = dig[j];
    u32 lpos = lstart[d] + whist[w][d] + rnk[j];
    sk[lpos] = kk[j];
    sv[lpos] = vv[j];
  }
  __syncthreads();
#pragma unroll
  for (int r = 0; r < 16; r++) {
    int idx = t + r * 512;
    u32 key = sk[idx];
    u32 d = (key >> shift) & 255u;
    u32 gpos = gdelta[d] + (u32)idx;
    u32 val = sv[idx];
    vout[gpos] = val;
    if (mode == 0) kout[gpos] = key;
  }
}

// last sort2 pass: LDS reorder, then write A-table row float4(A0,A1,A2,0) at sorted pos
__global__ __launch_bounds__(512) void k_scatter_ops(const u32* __restrict__ kin, const u32* __restrict__ vin,
                                                     const u32* __restrict__ gbase, int shift, int nB,
                                                     const u32* __restrict__ addr, float4* __restrict__ ops) {
  __shared__ u32 sk[8192], sv[8192];
  __shared__ u32 whist[8][256];
  __shared__ u32 sbase[256], lstart[256], gdelta[256], red[256];
  int t = threadIdx.x, b = blockIdx.x;
  int base = b * 8192;
  if (t < 256) {
#pragma unroll
    for (int w2 = 0; w2 < 8; w2++) whist[w2][t] = 0;
    sbase[t] = gbase[t * nB + b];
  }
  __syncthreads();
  int w = t >> 6, lane = t & 63;
  u64 lowmask = (1ull << lane) - 1ull;
  u32 kk[16], vv[16], dig[16], rnk[16];
#pragma unroll
  for (int j = 0; j < 16; j++) {
    int idx = base + w * 1024 + j * 64 + lane;
    kk[j] = kin[idx];
    vv[j] = vin[idx];
  }
#pragma unroll
  for (int j = 0; j < 16; j++) {
    u32 d = (kk[j] >> shift) & 255u;
    u64 m = ~0ull;
#pragma unroll
    for (int bit = 0; bit < 8; bit++) {
      u64 bal = __ballot((d >> bit) & 1u);
      m &= ((d >> bit) & 1u) ? bal : ~bal;
    }
    u32 rr = (u32)__popcll(m & lowmask);
    u32 cnt = (u32)__popcll(m);
    u32 prev = whist[w][d];
    if (rr == 0) whist[w][d] = prev + cnt;
    dig[j] = d;
    rnk[j] = prev + rr;
  }
  __syncthreads();
  u32 tot = 0;
  if (t < 256) {
    u32 sacc = 0;
#pragma unroll
    for (int ww = 0; ww < 8; ww++) { u32 v = whist[ww][t]; whist[ww][t] = sacc; sacc += v; }
    tot = sacc;
    red[t] = tot;
  }
  __syncthreads();
  for (int off = 1; off < 256; off <<= 1) {
    u32 y = (t < 256 && t >= off) ? red[t - off] : 0u;
    __syncthreads();
    if (t < 256) red[t] += y;
    __syncthreads();
  }
  if (t < 256) {
    u32 lst = red[t] - tot;
    lstart[t] = lst;
    gdelta[t] = sbase[t] - lst;
  }
  __syncthreads();
#pragma unroll
  for (int j = 0; j < 16; j++) {
    u32 d = dig[j];
    u32 lpos = lstart[d] + whist[w][d] + rnk[j];
    sk[lpos] = kk[j];
    sv[lpos] = vv[j];
  }
  __syncthreads();
#pragma unroll
  for (int r = 0; r < 16; r++) {
    int idx = t + r * 512;
    u32 key = sk[idx];
    u32 d = (key >> shift) & 255u;
    u32 gpos = gdelta[d] + (u32)idx;
    u32 rv = sv[idx];
    int i = (int)(rv >> 9), jj = (int)(rv & 511);
    float A0 = (float)addr[(i << 10) + jj];
    float A1 = (float)addr[OFF1 + (i << 10) + jj];
    float A2 = (float)addr[OFF2 + (int)rv];
    ops[gpos] = make_float4(A0, A1, A2, 0.0f);
  }
}

// merged 3 convs: streaming 1->8ch 3x3 SAME on addr-as-float, relu,
// bf16x8 pack scattered directly to memory-position order featsM[addr[label]].
__global__ __launch_bounds__(256) void k_conv(const u32* __restrict__ addr,
                                              const float* __restrict__ cw0, const float* __restrict__ cb0,
                                              const float* __restrict__ cw1, const float* __restrict__ cb1,
                                              const float* __restrict__ cw2, const float* __restrict__ cb2,
                                              u16* __restrict__ featsM) {
  int b = blockIdx.x;
  int H, W, lw, off;
  const float *cw, *cb;
  int pix;
  if (b < 4096)      { H = 1024; W = 1024; lw = 10; off = 0;    cw = cw0; cb = cb0; pix = b * 256; }
  else if (b < 8192) { H = 1024; W = 1024; lw = 10; off = OFF1; cw = cw1; cb = cb1; pix = (b - 4096) * 256; }
  else               { H = 512;  W = 512;  lw = 9;  off = OFF2; cw = cw2; cb = cb2; pix = (b - 8192) * 256; }
  pix += threadIdx.x;
  int i = pix >> lw, j = pix & (W - 1);
  u32 m = addr[off + pix];  // destination memory position
  float x[3][3];
#pragma unroll
  for (int dr = 0; dr < 3; dr++)
#pragma unroll
    for (int dc = 0; dc < 3; dc++) {
      int r = i + dr - 1, c = j + dc - 1;
      bool inb = ((unsigned)r < (unsigned)H) && ((unsigned)c < (unsigned)W);
      x[dr][dc] = inb ? (float)addr[off + r * W + c] : 0.0f;
    }
  float acc[8];
#pragma unroll
  for (int oc = 0; oc < 8; oc++) {
    float s = cb[oc];
#pragma unroll
    for (int dr = 0; dr < 3; dr++)
#pragma unroll
      for (int dc = 0; dc < 3; dc++)
        s = fmaf(x[dr][dc], cw[oc * 9 + dr * 3 + dc], s);
    acc[oc] = fmaxf(s, 0.0f);
  }
  uint4 pk;
  pk.x = pk_bf16(acc[0], acc[1]);
  pk.y = pk_bf16(acc[2], acc[3]);
  pk.z = pk_bf16(acc[4], acc[5]);
  pk.w = pk_bf16(acc[6], acc[7]);
  *(uint4*)(featsM + (size_t)m * 8) = pk;
}

// 8->16ch 3x3 conv + fused 4x4 pool, fully coalesced reads from featsM.
// Inner loop written as float2 pairs (oc even/odd) to expose v_pk_fma_f32 SLP.
__global__ __launch_bounds__(256) void k_memconv(const u16* __restrict__ featsM,
                                                 const float* __restrict__ wt,
                                                 const float* __restrict__ mb,
                                                 float* __restrict__ partials) {
  __shared__ float tile[34 * 80];
  __shared__ float pool_s[256 * 17];
  int t = threadIdx.x;
  int r0 = blockIdx.x * 32;
  for (int idx = t; idx < 34 * 8; idx += 256) {
    int rr = idx >> 3, g = idx & 7;
    int r = r0 - 1 + rr;
    float f[8];
    if ((unsigned)r < (unsigned)N_ROWS) {
      uint4 u = *(const uint4*)(featsM + (size_t)(r * 8 + g) * 8);
      f[0] = __uint_as_float(u.x << 16); f[1] = __uint_as_float(u.x & 0xffff0000u);
      f[2] = __uint_as_float(u.y << 16); f[3] = __uint_as_float(u.y & 0xffff0000u);
      f[4] = __uint_as_float(u.z << 16); f[5] = __uint_as_float(u.z & 0xffff0000u);
      f[6] = __uint_as_float(u.w << 16); f[7] = __uint_as_float(u.w & 0xffff0000u);
    } else {
#pragma unroll
      for (int c = 0; c < 8; c++) f[c] = 0.0f;
    }
#pragma unroll
    for (int c = 0; c < 8; c++) tile[rr * 80 + (g + 1) * 8 + c] = f[c];
  }
  for (int idx = t; idx < 34 * 16; idx += 256) {
    int rr = idx >> 4, k = idx & 15;
    int col = (k < 8) ? k : (64 + k);
    tile[rr * 80 + col] = 0.0f;
  }
  __syncthreads();
  int lr = t >> 3, l = t & 7;
  float2 acc2[8];
#pragma unroll
  for (int o2 = 0; o2 < 8; o2++) acc2[o2] = make_float2(mb[2 * o2], mb[2 * o2 + 1]);
#pragma unroll
  for (int dr = 0; dr < 3; dr++) {
#pragma unroll
    for (int dl = 0; dl < 3; dl++) {
      const float* src = &tile[(lr + dr) * 80 + (l + dl) * 8];
      float4 a0 = *(const float4*)(src);
      float4 a1 = *(const float4*)(src + 4);
      float xv[8] = {a0.x, a0.y, a0.z, a0.w, a1.x, a1.y, a1.z, a1.w};
      const float2* wp2 = (const float2*)(&wt[(dr * 3 + dl) * 128]);
#pragma unroll
      for (int ic = 0; ic < 8; ic++) {
        float xv1 = xv[ic];
#pragma unroll
        for (int o2 = 0; o2 < 8; o2++) {
          float2 w2 = wp2[ic * 8 + o2];
          acc2[o2].x = fmaf(xv1, w2.x, acc2[o2].x);
          acc2[o2].y = fmaf(xv1, w2.y, acc2[o2].y);
        }
      }
    }
  }
#pragma unroll
  for (int o2 = 0; o2 < 8; o2++) {
    pool_s[t * 17 + 2 * o2]     = fmaxf(acc2[o2].x, 0.0f);
    pool_s[t * 17 + 2 * o2 + 1] = fmaxf(acc2[o2].y, 0.0f);
  }
  __syncthreads();
  if (t < 64) {
    int oc = t >> 2, lb = t & 3;
    float s = 0.0f;
    for (int lr2 = 0; lr2 < 32; lr2++) {
      int t2 = lr2 * 8 + lb * 2;
      s += pool_s[t2 * 17 + oc] + pool_s[(t2 + 1) * 17 + oc];
    }
    partials[(size_t)(oc * 4 + lb) * 9216 + blockIdx.x] = s;
  }
}

__global__ __launch_bounds__(256) void k_pool_final(const float* __restrict__ partials,
                                                    float* __restrict__ flat) {
  int f = blockIdx.x;
  int oc = f >> 4, rb = (f >> 2) & 3, lb = f & 3;
  const float* src = partials + (size_t)(oc * 4 + lb) * 9216 + rb * 2304;
  double s = 0.0;
  for (int i = threadIdx.x; i < 2304; i += 256) s += (double)src[i];
  __shared__ double sd[256];
  sd[threadIdx.x] = s;
  __syncthreads();
  for (int off = 128; off > 0; off >>= 1) {
    if (threadIdx.x < off) sd[threadIdx.x] += sd[threadIdx.x + off];
    __syncthreads();
  }
  if (threadIdx.x == 0) flat[f] = (float)(sd[0] * (1.0 / 147456.0));
}

// one wave per 32 rows of proj_w; also emits sort2 keys+vals
__global__ __launch_bounds__(256) void k_matvec(const float* __restrict__ pw,
                                                const float* __restrict__ pb,
                                                const float* __restrict__ flat,
                                                float* __restrict__ out,
                                                u32* __restrict__ k2, u32* __restrict__ v2) {
  int t = threadIdx.x;
  int lane = t & 63;
  int g = (blockIdx.x * 256 + t) >> 6;
  float4 f4 = ((const float4*)flat)[lane];
  int row0 = g * 32;
  for (int it = 0; it < 32; it += 2) {
    int row = row0 + it;
    float4 wa = ((const float4*)(pw + (size_t)row * 256))[lane];
    float4 wb = ((const float4*)(pw + (size_t)(row + 1) * 256))[lane];
    float sa = wa.x * f4.x + wa.y * f4.y + wa.z * f4.z + wa.w * f4.w;
    float sb = wb.x * f4.x + wb.y * f4.y + wb.z * f4.z + wb.w * f4.w;
#pragma unroll
    for (int off = 32; off > 0; off >>= 1) {
      sa += __shfl_xor(sa, off, 64);
      sb += __shfl_xor(sb, off, 64);
    }
    if (lane == 0) {
      float ra = sa + pb[row], rb2 = sb + pb[row + 1];
      out[row] = ra;
      out[row + 1] = rb2;
      u32 ua = __float_as_uint(ra), ub = __float_as_uint(rb2);
      ua = (ua & 0x80000000u) ? ~ua : (ua | 0x80000000u);
      ub = (ub & 0x80000000u) ? ~ub : (ub | 0x80000000u);
      k2[row] = ua; k2[row + 1] = ub;
      v2[row] = (u32)row; v2[row + 1] = (u32)(row + 1);
    }
  }
}

__device__ inline double staged_pair(float x) {
  float h = fabsf(x);
  double mult = (h <= 2.f) ? 1.0 : (h <= 4.f) ? 1.5 : (h <= 8.f) ? 2.0 : (h <= 16.f) ? 3.0 : 5.0;
  double hh = (double)h;
  if (x > 0.f) return hh * mult;
  if (x < 0.f) return hh * hh * mult;
  return 0.0;
}

// penalty + finalize in one kernel: block sums -> f64 global atomics; last ticket writes out.
__global__ __launch_bounds__(256) void k_penalty_fin(const float4* __restrict__ ops,
                                                     double* __restrict__ pgp,
                                                     u32* __restrict__ bar,
                                                     float* __restrict__ out) {
  int t = threadIdx.x;
  int k = blockIdx.x * 256 + t;
  float4 a = ops[k];
  double intra = staged_pair(a.y - a.x) + staged_pair(a.z - a.y);
  double inter = 0.0;
  if (k < N_OPS - 1) {
    float4 b = ops[k + 1];
    inter = staged_pair(b.x - a.z);
  }
  __shared__ double s0[256], s1[256];
  s0[t] = inter;
  s1[t] = intra;
  __syncthreads();
  for (int off = 128; off > 0; off >>= 1) {
    if (t < off) {
      s0[t] += s0[t + off];
      s1[t] += s1[t + off];
    }
    __syncthreads();
  }
  if (t == 0) {
    atomicAdd(&pgp[0], s0[0]);
    atomicAdd(&pgp[1], s1[0]);
    __threadfence();
    u32 tk = atomicAdd(bar, 1u);
    if (tk == 1023u) {               // last block: all adds are L2-visible
      double a0 = atomicAdd(&pgp[0], 0.0);
      double a1 = atomicAdd(&pgp[1], 0.0);
      out[N_OPS] = (float)a0;
      out[N_OPS + 1] = (float)a1;
    }
  }
}

extern "C" void kernel_launch(void* const* d_in, const int* in_sizes, int n_in,
                              void* d_out, int out_size, void* d_ws, size_t ws_size,
                              hipStream_t stream) {
  const float* mem_logits = (const float*)d_in[0];
  const float* cw0 = (const float*)d_in[1];
  const float* cb0 = (const float*)d_in[2];
  const float* cw1 = (const float*)d_in[3];
  const float* cb1 = (const float*)d_in[4];
  const float* cw2 = (const float*)d_in[5];
  const float* cb2 = (const float*)d_in[6];
  const float* mw  = (const float*)d_in[7];
  const float* mbb = (const float*)d_in[8];
  const float* pw  = (const float*)d_in[9];
  const float* pb  = (const float*)d_in[10];
  float* out = (float*)d_out;
  char* ws = (char*)d_ws;

  u32* addr      = (u32*)(ws);
  u16* featsM    = (u16*)(ws + OFF_F8);
  u32* kA        = (u32*)(ws + OFF_F8);
  u32* kB        = (u32*)(ws + OFF_F8 + 9437184ull);
  u32* v0        = (u32*)(ws + OFF_F8 + 18874368ull);
  u32* v1        = (u32*)(ws + OFF_F8 + 28311552ull);
  u32* counts0   = (u32*)(ws + OFF_C0);
  u32* pos       = (u32*)(ws + OFF_POS);
  float* partials= (float*)(ws + OFF_PART);
  float* flat    = (float*)(ws + OFF_FLAT);
  float* wt      = (float*)(ws + OFF_WT);
  double* pgp    = (double*)(ws + OFF_PGP);
  u32* bar       = (u32*)(ws + OFF_BAR);
  float4* ops    = (float4*)(ws + OFF_OPS);
  u32* k2A       = (u32*)(ws + OFF_S2);
  u32* k2B       = (u32*)(ws + OFF_S2 + 1048576ull);
  u32* v2A       = (u32*)(ws + OFF_S2 + 2097152ull);
  u32* v2B       = (u32*)(ws + OFF_S2 + 3145728ull);

  // ---- sort1: keys + pass-0 hist fused in k_front; passes 1,2 use k_hist ----
  k_front<<<289, 256, 0, stream>>>(mem_logits, kA, counts0, mw, wt, bar, pgp);
  k_scan_par<<<256, 256, 0, stream>>>(counts0, pos, 288);
  k_scatter<<<288, 512, 0, stream>>>(kA, nullptr, kB, v0, pos, 8, 288, 1, 0);
  k_hist<<<288, 512, 0, stream>>>(kB, counts0, 16, 288);
  k_scan_par<<<256, 256, 0, stream>>>(counts0, pos, 288);
  k_scatter<<<288, 512, 0, stream>>>(kB, v0, kA, v1, pos, 16, 288, 0, 0);
  k_hist<<<288, 512, 0, stream>>>(kA, counts0, 24, 288);
  k_scan_par<<<256, 256, 0, stream>>>(counts0, pos, 288);
  k_scatter<<<288, 512, 0, stream>>>(kA, v1, nullptr, addr, pos, 24, 288, 0, 1);

  // ---- streaming convs (scatter to memory order), coalesced memconv + pool ----
  k_conv<<<9216, 256, 0, stream>>>(addr, cw0, cb0, cw1, cb1, cw2, cb2, featsM);
  k_memconv<<<9216, 256, 0, stream>>>(featsM, wt, mbb, partials);
  k_pool_final<<<256, 256, 0, stream>>>(partials, flat);

  // ---- projection matvec -> op_logits + sort2 keys ----
  k_matvec<<<2048, 256, 0, stream>>>(pw, pb, flat, out, k2A, v2A);

  // ---- sort2: 3 passes over bits [8..32); final pass emits A-table ----
  k_hist<<<32, 512, 0, stream>>>(k2A, counts0, 8, 32);
  k_scan_par<<<256, 256, 0, stream>>>(counts0, pos, 32);
  k_scatter<<<32, 512, 0, stream>>>(k2A, v2A, k2B, v2B, pos, 8, 32, 0, 0);
  k_hist<<<32, 512, 0, stream>>>(k2B, counts0, 16, 32);
  k_scan_par<<<256, 256, 0, stream>>>(counts0, pos, 32);
  k_scatter<<<32, 512, 0, stream>>>(k2B, v2B, k2A, v2A, pos, 16, 32, 0, 0);
  k_hist<<<32, 512, 0, stream>>>(k2A, counts0, 24, 32);
  k_scan_par<<<256, 256, 0, stream>>>(counts0, pos, 32);
  k_scatter_ops<<<32, 512, 0, stream>>>(k2A, v2A, pos, 24, 32, addr, ops);

  // ---- penalties + finalize (single kernel, f64 atomics + ticket) ----
  k_penalty_fin<<<1024, 256, 0, stream>>>(ops, pgp, bar, out);
}

// Round 5
// 818.790 us; speedup vs baseline: 1.0309x; 1.0309x over previous
//
#include <hip/hip_runtime.h>
#include <cstdint>
#include <cstddef>

typedef unsigned int u32;
typedef unsigned short u16;
typedef unsigned long long u64;

#define NUM_EL 2359296
#define N_ROWS 294912
#define N_OPS  262144
#define OFF1   1048576
#define OFF2   2097152

// ---------------- workspace layout (bytes) ----------------
// addr:    [0, 9437184)            u32[NUM_EL]
// featsM:  [18874368, 56623104)    bf16[NUM_EL*8] memory-position order (37.75MB)
//          sort1 scratch overlays (dead before k_conv):
//    kA=+0, kB=+9437184, v0=+18874368, v1=+28311552
// counts:  [56623104, 56918016)    u32[256*288]
// pos:     [56918016, 57212928)    u32[256*288]
// part:    [57212928, 59572224)    float[64*9216]
// flat:    [59572224, 59573248)    float[256]
// wt:      [59573248, 59577856)    float[1152]
// ppart:   [59577856, 59594240)    double[2*1024]
// ops:     [59594240, 63788544)    float4[N_OPS]
// k2A/k2B/v2A/v2B: [63788544, +4MB)
#define OFF_F8     18874368ull
#define OFF_COUNTS 56623104ull
#define OFF_POS    56918016ull
#define OFF_PART   57212928ull
#define OFF_FLAT   59572224ull
#define OFF_WT     59573248ull
#define OFF_PPART  59577856ull
#define OFF_OPS    59594240ull
#define OFF_S2     63788544ull

__device__ inline u32 pk_bf16(float a, float b) {  // RNE pack of 2 floats -> 2 bf16
  u32 ua = __float_as_uint(a), ub = __float_as_uint(b);
  ua = (ua + 0x7fffu + ((ua >> 16) & 1u)) >> 16;
  ub = (ub + 0x7fffu + ((ub >> 16) & 1u)) >> 16;
  return ua | (ub << 16);
}

// front: sort1 keys + fused pass-0 histogram (blocks 0..287, 8192-elem tiles, LDS atomics
// only -- strictly cheaper than a separate k_hist pass which re-reads 9.4MB),
// weight transpose (block 288).
__global__ __launch_bounds__(256) void k_front(const float* __restrict__ x,
                                               u32* __restrict__ keys,
                                               u32* __restrict__ counts0,
                                               const float* __restrict__ mw, float* __restrict__ wt) {
  int b = blockIdx.x, t = threadIdx.x;
  if (b < 288) {
    __shared__ u32 h[256];
    h[t] = 0u;
    __syncthreads();
    int base = b * 8192;
#pragma unroll
    for (int k = 0; k < 32; k++) {
      int i = base + k * 256 + t;
      u32 u = __float_as_uint(x[i]);
      u = (u & 0x80000000u) ? ~u : (u | 0x80000000u);
      keys[i] = u;
      atomicAdd(&h[(u >> 8) & 255u], 1u);
    }
    __syncthreads();
    counts0[t * 288 + b] = h[t];  // digit-major
  } else {
    for (int i = t; i < 1152; i += 256) {
      int oc = i & 15;
      int rest = i >> 4;
      int ic = rest & 7;
      int p = rest >> 3;
      int dr = p / 3, dl = p % 3;
      wt[i] = mw[((oc * 8 + ic) * 3 + dr) * 3 + dl];
    }
  }
}

// 512 threads, 8192-elem tile, 16 keys/thread. LDS histogram, coalesced output.
__global__ __launch_bounds__(512) void k_hist(const u32* __restrict__ keys,
                                              u32* __restrict__ counts, int shift, int nB) {
  __shared__ u32 h[256];
  int t = threadIdx.x;
  if (t < 256) h[t] = 0;
  __syncthreads();
  int base = blockIdx.x * 8192;
#pragma unroll
  for (int k = 0; k < 16; k++) {
    u32 d = (keys[base + t + k * 512] >> shift) & 255u;
    atomicAdd(&h[d], 1u);
  }
  __syncthreads();
  if (t < 256) counts[t * nB + blockIdx.x] = h[t];  // digit-major
}

// 256 blocks (one per digit): base = sum counts[0, d*nB), then row scan in LDS.
__global__ __launch_bounds__(256) void k_scan_par(const u32* __restrict__ counts,
                                                  u32* __restrict__ pos, int nB) {
  int d = blockIdx.x, t = threadIdx.x;
  __shared__ u32 red[256];
  u32 s = 0;
  u32 lim = (u32)(d * nB);
  for (u32 i = t; i < lim; i += 256) s += counts[i];
  red[t] = s;
  __syncthreads();
  for (int off = 128; off > 0; off >>= 1) {
    if (t < off) red[t] += red[t + off];
    __syncthreads();
  }
  u32 base = red[0];
  __syncthreads();
  int chunk = (nB + 255) / 256;  // 2 for nB=288, 1 for nB=32
  int i0 = t * chunk;
  u32 loc[4];
  u32 lsum = 0;
#pragma unroll 4
  for (int k = 0; k < chunk; k++) {
    int i = i0 + k;
    u32 v = (i < nB) ? counts[d * nB + i] : 0u;
    loc[k] = lsum;
    lsum += v;
  }
  red[t] = lsum;
  __syncthreads();
  for (int off = 1; off < 256; off <<= 1) {
    u32 y = (t >= off) ? red[t - off] : 0u;
    __syncthreads();
    red[t] += y;
    __syncthreads();
  }
  u32 excl = red[t] - lsum;
#pragma unroll 4
  for (int k = 0; k < chunk; k++) {
    int i = i0 + k;
    if (i < nB) pos[d * nB + i] = base + excl + loc[k];
  }
}

// Stable scatter, 8192 tile, LDS reorder-by-digit -> coalesced global runs.
// gen_iota: vals = global index (pass 0, vin unused).
// mode: 0 = write keys+vals; 1 = write vals only (final pass, keys dropped)
__global__ __launch_bounds__(512) void k_scatter(const u32* __restrict__ kin, const u32* __restrict__ vin,
                                                 u32* __restrict__ kout, u32* __restrict__ vout,
                                                 const u32* __restrict__ gbase, int shift, int nB,
                                                 int gen_iota, int mode) {
  __shared__ u32 sk[8192], sv[8192];
  __shared__ u32 whist[8][256];
  __shared__ u32 sbase[256], lstart[256], gdelta[256], red[256];
  int t = threadIdx.x, b = blockIdx.x;
  int base = b * 8192;
  if (t < 256) {
#pragma unroll
    for (int w2 = 0; w2 < 8; w2++) whist[w2][t] = 0;
    sbase[t] = gbase[t * nB + b];
  }
  __syncthreads();
  int w = t >> 6, lane = t & 63;
  u64 lowmask = (1ull << lane) - 1ull;
  u32 kk[16], vv[16], dig[16], rnk[16];
#pragma unroll
  for (int j = 0; j < 16; j++) {
    int idx = base + w * 1024 + j * 64 + lane;
    kk[j] = kin[idx];
    vv[j] = gen_iota ? (u32)idx : vin[idx];
  }
#pragma unroll
  for (int j = 0; j < 16; j++) {
    u32 d = (kk[j] >> shift) & 255u;
    u64 m = ~0ull;
#pragma unroll
    for (int bit = 0; bit < 8; bit++) {
      u64 bal = __ballot((d >> bit) & 1u);
      m &= ((d >> bit) & 1u) ? bal : ~bal;
    }
    u32 rr = (u32)__popcll(m & lowmask);
    u32 cnt = (u32)__popcll(m);
    u32 prev = whist[w][d];        // wave-synchronous LDS read
    if (rr == 0) whist[w][d] = prev + cnt;
    dig[j] = d;
    rnk[j] = prev + rr;
  }
  __syncthreads();
  u32 tot = 0;
  if (t < 256) {
    u32 sacc = 0;
#pragma unroll
    for (int ww = 0; ww < 8; ww++) { u32 v = whist[ww][t]; whist[ww][t] = sacc; sacc += v; }
    tot = sacc;
    red[t] = tot;
  }
  __syncthreads();
  for (int off = 1; off < 256; off <<= 1) {
    u32 y = (t < 256 && t >= off) ? red[t - off] : 0u;
    __syncthreads();
    if (t < 256) red[t] += y;
    __syncthreads();
  }
  if (t < 256) {
    u32 lst = red[t] - tot;
    lstart[t] = lst;
    gdelta[t] = sbase[t] - lst;
  }
  __syncthreads();
#pragma unroll
  for (int j = 0; j < 16; j++) {
    u32 d = dig[j];
    u32 lpos = lstart[d] + whist[w][d] + rnk[j];
    sk[lpos] = kk[j];
    sv[lpos] = vv[j];
  }
  __syncthreads();
#pragma unroll
  for (int r = 0; r < 16; r++) {
    int idx = t + r * 512;
    u32 key = sk[idx];
    u32 d = (key >> shift) & 255u;
    u32 gpos = gdelta[d] + (u32)idx;
    u32 val = sv[idx];
    vout[gpos] = val;
    if (mode == 0) kout[gpos] = key;
  }
}

// last sort2 pass: LDS reorder, then write A-table row float4(A0,A1,A2,0) at sorted pos
__global__ __launch_bounds__(512) void k_scatter_ops(const u32* __restrict__ kin, const u32* __restrict__ vin,
                                                     const u32* __restrict__ gbase, int shift, int nB,
                                                     const u32* __restrict__ addr, float4* __restrict__ ops) {
  __shared__ u32 sk[8192], sv[8192];
  __shared__ u32 whist[8][256];
  __shared__ u32 sbase[256], lstart[256], gdelta[256], red[256];
  int t = threadIdx.x, b = blockIdx.x;
  int base = b * 8192;
  if (t < 256) {
#pragma unroll
    for (int w2 = 0; w2 < 8; w2++) whist[w2][t] = 0;
    sbase[t] = gbase[t * nB + b];
  }
  __syncthreads();
  int w = t >> 6, lane = t & 63;
  u64 lowmask = (1ull << lane) - 1ull;
  u32 kk[16], vv[16], dig[16], rnk[16];
#pragma unroll
  for (int j = 0; j < 16; j++) {
    int idx = base + w * 1024 + j * 64 + lane;
    kk[j] = kin[idx];
    vv[j] = vin[idx];
  }
#pragma unroll
  for (int j = 0; j < 16; j++) {
    u32 d = (kk[j] >> shift) & 255u;
    u64 m = ~0ull;
#pragma unroll
    for (int bit = 0; bit < 8; bit++) {
      u64 bal = __ballot((d >> bit) & 1u);
      m &= ((d >> bit) & 1u) ? bal : ~bal;
    }
    u32 rr = (u32)__popcll(m & lowmask);
    u32 cnt = (u32)__popcll(m);
    u32 prev = whist[w][d];
    if (rr == 0) whist[w][d] = prev + cnt;
    dig[j] = d;
    rnk[j] = prev + rr;
  }
  __syncthreads();
  u32 tot = 0;
  if (t < 256) {
    u32 sacc = 0;
#pragma unroll
    for (int ww = 0; ww < 8; ww++) { u32 v = whist[ww][t]; whist[ww][t] = sacc; sacc += v; }
    tot = sacc;
    red[t] = tot;
  }
  __syncthreads();
  for (int off = 1; off < 256; off <<= 1) {
    u32 y = (t < 256 && t >= off) ? red[t - off] : 0u;
    __syncthreads();
    if (t < 256) red[t] += y;
    __syncthreads();
  }
  if (t < 256) {
    u32 lst = red[t] - tot;
    lstart[t] = lst;
    gdelta[t] = sbase[t] - lst;
  }
  __syncthreads();
#pragma unroll
  for (int j = 0; j < 16; j++) {
    u32 d = dig[j];
    u32 lpos = lstart[d] + whist[w][d] + rnk[j];
    sk[lpos] = kk[j];
    sv[lpos] = vv[j];
  }
  __syncthreads();
#pragma unroll
  for (int r = 0; r < 16; r++) {
    int idx = t + r * 512;
    u32 key = sk[idx];
    u32 d = (key >> shift) & 255u;
    u32 gpos = gdelta[d] + (u32)idx;
    u32 rv = sv[idx];
    int i = (int)(rv >> 9), jj = (int)(rv & 511);
    float A0 = (float)addr[(i << 10) + jj];
    float A1 = (float)addr[OFF1 + (i << 10) + jj];
    float A2 = (float)addr[OFF2 + (int)rv];
    ops[gpos] = make_float4(A0, A1, A2, 0.0f);
  }
}

// merged 3 convs: streaming 1->8ch 3x3 SAME on addr-as-float, relu,
// bf16x8 pack scattered directly to memory-position order featsM[addr[label]].
__global__ __launch_bounds__(256) void k_conv(const u32* __restrict__ addr,
                                              const float* __restrict__ cw0, const float* __restrict__ cb0,
                                              const float* __restrict__ cw1, const float* __restrict__ cb1,
                                              const float* __restrict__ cw2, const float* __restrict__ cb2,
                                              u16* __restrict__ featsM) {
  int b = blockIdx.x;
  int H, W, lw, off;
  const float *cw, *cb;
  int pix;
  if (b < 4096)      { H = 1024; W = 1024; lw = 10; off = 0;    cw = cw0; cb = cb0; pix = b * 256; }
  else if (b < 8192) { H = 1024; W = 1024; lw = 10; off = OFF1; cw = cw1; cb = cb1; pix = (b - 4096) * 256; }
  else               { H = 512;  W = 512;  lw = 9;  off = OFF2; cw = cw2; cb = cb2; pix = (b - 8192) * 256; }
  pix += threadIdx.x;
  int i = pix >> lw, j = pix & (W - 1);
  u32 m = addr[off + pix];  // destination memory position
  float x[3][3];
#pragma unroll
  for (int dr = 0; dr < 3; dr++)
#pragma unroll
    for (int dc = 0; dc < 3; dc++) {
      int r = i + dr - 1, c = j + dc - 1;
      bool inb = ((unsigned)r < (unsigned)H) && ((unsigned)c < (unsigned)W);
      x[dr][dc] = inb ? (float)addr[off + r * W + c] : 0.0f;
    }
  float acc[8];
#pragma unroll
  for (int oc = 0; oc < 8; oc++) {
    float s = cb[oc];
#pragma unroll
    for (int dr = 0; dr < 3; dr++)
#pragma unroll
      for (int dc = 0; dc < 3; dc++)
        s = fmaf(x[dr][dc], cw[oc * 9 + dr * 3 + dc], s);
    acc[oc] = fmaxf(s, 0.0f);
  }
  uint4 pk;
  pk.x = pk_bf16(acc[0], acc[1]);
  pk.y = pk_bf16(acc[2], acc[3]);
  pk.z = pk_bf16(acc[4], acc[5]);
  pk.w = pk_bf16(acc[6], acc[7]);
  *(uint4*)(featsM + (size_t)m * 8) = pk;
}

// 8->16ch 3x3 conv + fused 4x4 pool, fully coalesced reads from featsM.
__global__ __launch_bounds__(256) void k_memconv(const u16* __restrict__ featsM,
                                                 const float* __restrict__ wt,
                                                 const float* __restrict__ mb,
                                                 float* __restrict__ partials) {
  __shared__ float tile[34 * 80];
  __shared__ float pool_s[256 * 17];
  int t = threadIdx.x;
  int r0 = blockIdx.x * 32;
  for (int idx = t; idx < 34 * 8; idx += 256) {
    int rr = idx >> 3, g = idx & 7;
    int r = r0 - 1 + rr;
    float f[8];
    if ((unsigned)r < (unsigned)N_ROWS) {
      uint4 u = *(const uint4*)(featsM + (size_t)(r * 8 + g) * 8);
      f[0] = __uint_as_float(u.x << 16); f[1] = __uint_as_float(u.x & 0xffff0000u);
      f[2] = __uint_as_float(u.y << 16); f[3] = __uint_as_float(u.y & 0xffff0000u);
      f[4] = __uint_as_float(u.z << 16); f[5] = __uint_as_float(u.z & 0xffff0000u);
      f[6] = __uint_as_float(u.w << 16); f[7] = __uint_as_float(u.w & 0xffff0000u);
    } else {
#pragma unroll
      for (int c = 0; c < 8; c++) f[c] = 0.0f;
    }
#pragma unroll
    for (int c = 0; c < 8; c++) tile[rr * 80 + (g + 1) * 8 + c] = f[c];
  }
  for (int idx = t; idx < 34 * 16; idx += 256) {
    int rr = idx >> 4, k = idx & 15;
    int col = (k < 8) ? k : (64 + k);
    tile[rr * 80 + col] = 0.0f;
  }
  __syncthreads();
  int lr = t >> 3, l = t & 7;
  float acc[16];
#pragma unroll
  for (int oc = 0; oc < 16; oc++) acc[oc] = mb[oc];
#pragma unroll
  for (int dr = 0; dr < 3; dr++) {
#pragma unroll
    for (int dl = 0; dl < 3; dl++) {
      const float* src = &tile[(lr + dr) * 80 + (l + dl) * 8];
      float4 a0 = *(const float4*)(src);
      float4 a1 = *(const float4*)(src + 4);
      float xv[8] = {a0.x, a0.y, a0.z, a0.w, a1.x, a1.y, a1.z, a1.w};
      const float* wp = &wt[(dr * 3 + dl) * 128];
#pragma unroll
      for (int ic = 0; ic < 8; ic++) {
#pragma unroll
        for (int oc = 0; oc < 16; oc++)
          acc[oc] = fmaf(xv[ic], wp[ic * 16 + oc], acc[oc]);
      }
    }
  }
#pragma unroll
  for (int oc = 0; oc < 16; oc++) pool_s[t * 17 + oc] = fmaxf(acc[oc], 0.0f);
  __syncthreads();
  if (t < 64) {
    int oc = t >> 2, lb = t & 3;
    float s = 0.0f;
    for (int lr2 = 0; lr2 < 32; lr2++) {
      int t2 = lr2 * 8 + lb * 2;
      s += pool_s[t2 * 17 + oc] + pool_s[(t2 + 1) * 17 + oc];
    }
    partials[(size_t)(oc * 4 + lb) * 9216 + blockIdx.x] = s;
  }
}

__global__ __launch_bounds__(256) void k_pool_final(const float* __restrict__ partials,
                                                    float* __restrict__ flat) {
  int f = blockIdx.x;
  int oc = f >> 4, rb = (f >> 2) & 3, lb = f & 3;
  const float* src = partials + (size_t)(oc * 4 + lb) * 9216 + rb * 2304;
  double s = 0.0;
  for (int i = threadIdx.x; i < 2304; i += 256) s += (double)src[i];
  __shared__ double sd[256];
  sd[threadIdx.x] = s;
  __syncthreads();
  for (int off = 128; off > 0; off >>= 1) {
    if (threadIdx.x < off) sd[threadIdx.x] += sd[threadIdx.x + off];
    __syncthreads();
  }
  if (threadIdx.x == 0) flat[f] = (float)(sd[0] * (1.0 / 147456.0));
}

// one wave per 32 rows of proj_w; also emits sort2 keys+vals
__global__ __launch_bounds__(256) void k_matvec(const float* __restrict__ pw,
                                                const float* __restrict__ pb,
                                                const float* __restrict__ flat,
                                                float* __restrict__ out,
                                                u32* __restrict__ k2, u32* __restrict__ v2) {
  int t = threadIdx.x;
  int lane = t & 63;
  int g = (blockIdx.x * 256 + t) >> 6;
  float4 f4 = ((const float4*)flat)[lane];
  int row0 = g * 32;
  for (int it = 0; it < 32; it += 2) {
    int row = row0 + it;
    float4 wa = ((const float4*)(pw + (size_t)row * 256))[lane];
    float4 wb = ((const float4*)(pw + (size_t)(row + 1) * 256))[lane];
    float sa = wa.x * f4.x + wa.y * f4.y + wa.z * f4.z + wa.w * f4.w;
    float sb = wb.x * f4.x + wb.y * f4.y + wb.z * f4.z + wb.w * f4.w;
#pragma unroll
    for (int off = 32; off > 0; off >>= 1) {
      sa += __shfl_xor(sa, off, 64);
      sb += __shfl_xor(sb, off, 64);
    }
    if (lane == 0) {
      float ra = sa + pb[row], rb2 = sb + pb[row + 1];
      out[row] = ra;
      out[row + 1] = rb2;
      u32 ua = __float_as_uint(ra), ub = __float_as_uint(rb2);
      ua = (ua & 0x80000000u) ? ~ua : (ua | 0x80000000u);
      ub = (ub & 0x80000000u) ? ~ub : (ub | 0x80000000u);
      k2[row] = ua; k2[row + 1] = ub;
      v2[row] = (u32)row; v2[row + 1] = (u32)(row + 1);
    }
  }
}

__device__ inline double staged_pair(float x) {
  float h = fabsf(x);
  double mult = (h <= 2.f) ? 1.0 : (h <= 4.f) ? 1.5 : (h <= 8.f) ? 2.0 : (h <= 16.f) ? 3.0 : 5.0;
  double hh = (double)h;
  if (x > 0.f) return hh * mult;
  if (x < 0.f) return hh * hh * mult;
  return 0.0;
}

__global__ __launch_bounds__(256) void k_penalty(const float4* __restrict__ ops,
                                                 double* __restrict__ ppart) {
  int k = blockIdx.x * 256 + threadIdx.x;
  float4 a = ops[k];
  double intra = staged_pair(a.y - a.x) + staged_pair(a.z - a.y);
  double inter = 0.0;
  if (k < N_OPS - 1) {
    float4 b = ops[k + 1];
    inter = staged_pair(b.x - a.z);
  }
  __shared__ double s0[256], s1[256];
  s0[threadIdx.x] = inter;
  s1[threadIdx.x] = intra;
  __syncthreads();
  for (int off = 128; off > 0; off >>= 1) {
    if (threadIdx.x < off) {
      s0[threadIdx.x] += s0[threadIdx.x + off];
      s1[threadIdx.x] += s1[threadIdx.x + off];
    }
    __syncthreads();
  }
  if (threadIdx.x == 0) {
    ppart[blockIdx.x] = s0[0];
    ppart[1024 + blockIdx.x] = s1[0];
  }
}

__global__ __launch_bounds__(256) void k_finalize(const double* __restrict__ ppart,
                                                  float* __restrict__ out) {
  int t = threadIdx.x;
  double s0 = 0.0, s1 = 0.0;
  for (int i = t; i < 1024; i += 256) {
    s0 += ppart[i];
    s1 += ppart[1024 + i];
  }
  __shared__ double a0[256], a1[256];
  a0[t] = s0;
  a1[t] = s1;
  __syncthreads();
  for (int off = 128; off > 0; off >>= 1) {
    if (t < off) {
      a0[t] += a0[t + off];
      a1[t] += a1[t + off];
    }
    __syncthreads();
  }
  if (t == 0) {
    out[N_OPS] = (float)a0[0];
    out[N_OPS + 1] = (float)a1[0];
  }
}

extern "C" void kernel_launch(void* const* d_in, const int* in_sizes, int n_in,
                              void* d_out, int out_size, void* d_ws, size_t ws_size,
                              hipStream_t stream) {
  const float* mem_logits = (const float*)d_in[0];
  const float* cw0 = (const float*)d_in[1];
  const float* cb0 = (const float*)d_in[2];
  const float* cw1 = (const float*)d_in[3];
  const float* cb1 = (const float*)d_in[4];
  const float* cw2 = (const float*)d_in[5];
  const float* cb2 = (const float*)d_in[6];
  const float* mw  = (const float*)d_in[7];
  const float* mbb = (const float*)d_in[8];
  const float* pw  = (const float*)d_in[9];
  const float* pb  = (const float*)d_in[10];
  float* out = (float*)d_out;
  char* ws = (char*)d_ws;

  u32* addr      = (u32*)(ws);
  u16* featsM    = (u16*)(ws + OFF_F8);
  u32* kA        = (u32*)(ws + OFF_F8);
  u32* kB        = (u32*)(ws + OFF_F8 + 9437184ull);
  u32* v0        = (u32*)(ws + OFF_F8 + 18874368ull);
  u32* v1        = (u32*)(ws + OFF_F8 + 28311552ull);
  u32* counts    = (u32*)(ws + OFF_COUNTS);
  u32* pos       = (u32*)(ws + OFF_POS);
  float* partials= (float*)(ws + OFF_PART);
  float* flat    = (float*)(ws + OFF_FLAT);
  float* wt      = (float*)(ws + OFF_WT);
  double* ppart  = (double*)(ws + OFF_PPART);
  float4* ops    = (float4*)(ws + OFF_OPS);
  u32* k2A       = (u32*)(ws + OFF_S2);
  u32* k2B       = (u32*)(ws + OFF_S2 + 1048576ull);
  u32* v2A       = (u32*)(ws + OFF_S2 + 2097152ull);
  u32* v2B       = (u32*)(ws + OFF_S2 + 3145728ull);

  // ---- sort1: keys + pass-0 hist fused in k_front; passes 1,2 use k_hist ----
  k_front<<<289, 256, 0, stream>>>(mem_logits, kA, counts, mw, wt);
  k_scan_par<<<256, 256, 0, stream>>>(counts, pos, 288);
  k_scatter<<<288, 512, 0, stream>>>(kA, nullptr, kB, v0, pos, 8, 288, 1, 0);
  k_hist<<<288, 512, 0, stream>>>(kB, counts, 16, 288);
  k_scan_par<<<256, 256, 0, stream>>>(counts, pos, 288);
  k_scatter<<<288, 512, 0, stream>>>(kB, v0, kA, v1, pos, 16, 288, 0, 0);
  k_hist<<<288, 512, 0, stream>>>(kA, counts, 24, 288);
  k_scan_par<<<256, 256, 0, stream>>>(counts, pos, 288);
  k_scatter<<<288, 512, 0, stream>>>(kA, v1, nullptr, addr, pos, 24, 288, 0, 1);

  // ---- streaming convs (scatter to memory order), coalesced memconv + pool ----
  k_conv<<<9216, 256, 0, stream>>>(addr, cw0, cb0, cw1, cb1, cw2, cb2, featsM);
  k_memconv<<<9216, 256, 0, stream>>>(featsM, wt, mbb, partials);
  k_pool_final<<<256, 256, 0, stream>>>(partials, flat);

  // ---- projection matvec -> op_logits + sort2 keys ----
  k_matvec<<<2048, 256, 0, stream>>>(pw, pb, flat, out, k2A, v2A);

  // ---- sort2: 3 passes over bits [8..32); final pass emits A-table ----
  k_hist<<<32, 512, 0, stream>>>(k2A, counts, 8, 32);
  k_scan_par<<<256, 256, 0, stream>>>(counts, pos, 32);
  k_scatter<<<32, 512, 0, stream>>>(k2A, v2A, k2B, v2B, pos, 8, 32, 0, 0);
  k_hist<<<32, 512, 0, stream>>>(k2B, counts, 16, 32);
  k_scan_par<<<256, 256, 0, stream>>>(counts, pos, 32);
  k_scatter<<<32, 512, 0, stream>>>(k2B, v2B, k2A, v2A, pos, 16, 32, 0, 0);
  k_hist<<<32, 512, 0, stream>>>(k2A, counts, 24, 32);
  k_scan_par<<<256, 256, 0, stream>>>(counts, pos, 32);
  k_scatter_ops<<<32, 512, 0, stream>>>(k2A, v2A, pos, 24, 32, addr, ops);

  // ---- penalties (split two-kernel reduction, no global atomics) ----
  k_penalty<<<1024, 256, 0, stream>>>(ops, ppart);
  k_finalize<<<1, 256, 0, stream>>>(ppart, out);
}

// Round 6
// 752.063 us; speedup vs baseline: 1.1224x; 1.0887x over previous
//
#include <hip/hip_runtime.h>
#include <cstdint>
#include <cstddef>

typedef unsigned int u32;
typedef unsigned short u16;
typedef unsigned long long u64;
typedef __attribute__((ext_vector_type(8))) short short8;
typedef __attribute__((ext_vector_type(4))) float f32x4;

#define NUM_EL 2359296
#define N_ROWS 294912
#define N_OPS  262144
#define OFF1   1048576
#define OFF2   2097152

// ---------------- workspace layout (bytes) ----------------
// addr:    [0, 9437184)            u32[NUM_EL]
// featsM:  [18874368, 56623104)    bf16[NUM_EL*8] memory-position order (37.75MB)
//          sort1 scratch overlays (dead before k_conv):
//    kA=+0, kB=+9437184, v0=+18874368, v1=+28311552
// counts:  [56623104, 56918016)    u32[256*288]
// pos:     [56918016, 57212928)    u32[256*288]
// part:    [57212928, 59572224)    float[64*9216]
// flat:    [59572224, 59573248)    float[256]
// wtbT:    [59573248, 59577856)    bf16[16*96] weights transposed [oc][k] (k=tap*8+ic, pad 96)
// ppart:   [59577856, 59594240)    double[2*1024]
// ops:     [59594240, 63788544)    float4[N_OPS]
// k2A/k2B/v2A/v2B: [63788544, +4MB)
#define OFF_F8     18874368ull
#define OFF_COUNTS 56623104ull
#define OFF_POS    56918016ull
#define OFF_PART   57212928ull
#define OFF_FLAT   59572224ull
#define OFF_WT     59573248ull
#define OFF_PPART  59577856ull
#define OFF_OPS    59594240ull
#define OFF_S2     63788544ull

__device__ inline u32 pk_bf16(float a, float b) {  // RNE pack of 2 floats -> 2 bf16
  u32 ua = __float_as_uint(a), ub = __float_as_uint(b);
  ua = (ua + 0x7fffu + ((ua >> 16) & 1u)) >> 16;
  ub = (ub + 0x7fffu + ((ub >> 16) & 1u)) >> 16;
  return ua | (ub << 16);
}

__device__ inline u16 bf16_1(float a) {
  u32 ua = __float_as_uint(a);
  ua = (ua + 0x7fffu + ((ua >> 16) & 1u)) >> 16;
  return (u16)ua;
}

// front: sort1 keys + fused pass-0 histogram (blocks 0..287, LDS atomics only),
// bf16 weight transpose for MFMA memconv (block 288).
__global__ __launch_bounds__(256) void k_front(const float* __restrict__ x,
                                               u32* __restrict__ keys,
                                               u32* __restrict__ counts0,
                                               const float* __restrict__ mw, u16* __restrict__ wtbT) {
  int b = blockIdx.x, t = threadIdx.x;
  if (b < 288) {
    __shared__ u32 h[256];
    h[t] = 0u;
    __syncthreads();
    int base = b * 8192;
#pragma unroll
    for (int k = 0; k < 32; k++) {
      int i = base + k * 256 + t;
      u32 u = __float_as_uint(x[i]);
      u = (u & 0x80000000u) ? ~u : (u | 0x80000000u);
      keys[i] = u;
      atomicAdd(&h[(u >> 8) & 255u], 1u);
    }
    __syncthreads();
    counts0[t * 288 + b] = h[t];  // digit-major
  } else {
    // wtbT[oc*96 + k], k = (dr*3+dl)*8 + ic for k<72, zero-padded to 96.
    for (int i = t; i < 1536; i += 256) {
      int oc = i / 96, k = i % 96;
      u16 val = 0;
      if (k < 72) {
        int tap = k >> 3, ic = k & 7;
        int dr = tap / 3, dl = tap % 3;
        val = bf16_1(mw[((oc * 8 + ic) * 3 + dr) * 3 + dl]);
      }
      wtbT[i] = val;
    }
  }
}

// 512 threads, 8192-elem tile, 16 keys/thread. LDS histogram, coalesced output.
__global__ __launch_bounds__(512) void k_hist(const u32* __restrict__ keys,
                                              u32* __restrict__ counts, int shift, int nB) {
  __shared__ u32 h[256];
  int t = threadIdx.x;
  if (t < 256) h[t] = 0;
  __syncthreads();
  int base = blockIdx.x * 8192;
#pragma unroll
  for (int k = 0; k < 16; k++) {
    u32 d = (keys[base + t + k * 512] >> shift) & 255u;
    atomicAdd(&h[d], 1u);
  }
  __syncthreads();
  if (t < 256) counts[t * nB + blockIdx.x] = h[t];  // digit-major
}

// 256 blocks (one per digit): base = sum counts[0, d*nB), then row scan in LDS.
__global__ __launch_bounds__(256) void k_scan_par(const u32* __restrict__ counts,
                                                  u32* __restrict__ pos, int nB) {
  int d = blockIdx.x, t = threadIdx.x;
  __shared__ u32 red[256];
  u32 s = 0;
  u32 lim = (u32)(d * nB);
  for (u32 i = t; i < lim; i += 256) s += counts[i];
  red[t] = s;
  __syncthreads();
  for (int off = 128; off > 0; off >>= 1) {
    if (t < off) red[t] += red[t + off];
    __syncthreads();
  }
  u32 base = red[0];
  __syncthreads();
  int chunk = (nB + 255) / 256;  // 2 for nB=288, 1 for nB=32
  int i0 = t * chunk;
  u32 loc[4];
  u32 lsum = 0;
#pragma unroll 4
  for (int k = 0; k < chunk; k++) {
    int i = i0 + k;
    u32 v = (i < nB) ? counts[d * nB + i] : 0u;
    loc[k] = lsum;
    lsum += v;
  }
  red[t] = lsum;
  __syncthreads();
  for (int off = 1; off < 256; off <<= 1) {
    u32 y = (t >= off) ? red[t - off] : 0u;
    __syncthreads();
    red[t] += y;
    __syncthreads();
  }
  u32 excl = red[t] - lsum;
#pragma unroll 4
  for (int k = 0; k < chunk; k++) {
    int i = i0 + k;
    if (i < nB) pos[d * nB + i] = base + excl + loc[k];
  }
}

// Stable scatter, 8192 tile, LDS reorder-by-digit -> coalesced global runs.
// gen_iota: vals = global index (pass 0, vin unused).
// mode: 0 = write keys+vals; 1 = write vals only (final pass, keys dropped)
__global__ __launch_bounds__(512) void k_scatter(const u32* __restrict__ kin, const u32* __restrict__ vin,
                                                 u32* __restrict__ kout, u32* __restrict__ vout,
                                                 const u32* __restrict__ gbase, int shift, int nB,
                                                 int gen_iota, int mode) {
  __shared__ u32 sk[8192], sv[8192];
  __shared__ u32 whist[8][256];
  __shared__ u32 sbase[256], lstart[256], gdelta[256], red[256];
  int t = threadIdx.x, b = blockIdx.x;
  int base = b * 8192;
  if (t < 256) {
#pragma unroll
    for (int w2 = 0; w2 < 8; w2++) whist[w2][t] = 0;
    sbase[t] = gbase[t * nB + b];
  }
  __syncthreads();
  int w = t >> 6, lane = t & 63;
  u64 lowmask = (1ull << lane) - 1ull;
  u32 kk[16], vv[16], dig[16], rnk[16];
#pragma unroll
  for (int j = 0; j < 16; j++) {
    int idx = base + w * 1024 + j * 64 + lane;
    kk[j] = kin[idx];
    vv[j] = gen_iota ? (u32)idx : vin[idx];
  }
#pragma unroll
  for (int j = 0; j < 16; j++) {
    u32 d = (kk[j] >> shift) & 255u;
    u64 m = ~0ull;
#pragma unroll
    for (int bit = 0; bit < 8; bit++) {
      u64 bal = __ballot((d >> bit) & 1u);
      m &= ((d >> bit) & 1u) ? bal : ~bal;
    }
    u32 rr = (u32)__popcll(m & lowmask);
    u32 cnt = (u32)__popcll(m);
    u32 prev = whist[w][d];        // wave-synchronous LDS read
    if (rr == 0) whist[w][d] = prev + cnt;
    dig[j] = d;
    rnk[j] = prev + rr;
  }
  __syncthreads();
  u32 tot = 0;
  if (t < 256) {
    u32 sacc = 0;
#pragma unroll
    for (int ww = 0; ww < 8; ww++) { u32 v = whist[ww][t]; whist[ww][t] = sacc; sacc += v; }
    tot = sacc;
    red[t] = tot;
  }
  __syncthreads();
  for (int off = 1; off < 256; off <<= 1) {
    u32 y = (t < 256 && t >= off) ? red[t - off] : 0u;
    __syncthreads();
    if (t < 256) red[t] += y;
    __syncthreads();
  }
  if (t < 256) {
    u32 lst = red[t] - tot;
    lstart[t] = lst;
    gdelta[t] = sbase[t] - lst;
  }
  __syncthreads();
#pragma unroll
  for (int j = 0; j < 16; j++) {
    u32 d = dig[j];
    u32 lpos = lstart[d] + whist[w][d] + rnk[j];
    sk[lpos] = kk[j];
    sv[lpos] = vv[j];
  }
  __syncthreads();
#pragma unroll
  for (int r = 0; r < 16; r++) {
    int idx = t + r * 512;
    u32 key = sk[idx];
    u32 d = (key >> shift) & 255u;
    u32 gpos = gdelta[d] + (u32)idx;
    u32 val = sv[idx];
    vout[gpos] = val;
    if (mode == 0) kout[gpos] = key;
  }
}

// last sort2 pass: LDS reorder, then write A-table row float4(A0,A1,A2,0) at sorted pos
__global__ __launch_bounds__(512) void k_scatter_ops(const u32* __restrict__ kin, const u32* __restrict__ vin,
                                                     const u32* __restrict__ gbase, int shift, int nB,
                                                     const u32* __restrict__ addr, float4* __restrict__ ops) {
  __shared__ u32 sk[8192], sv[8192];
  __shared__ u32 whist[8][256];
  __shared__ u32 sbase[256], lstart[256], gdelta[256], red[256];
  int t = threadIdx.x, b = blockIdx.x;
  int base = b * 8192;
  if (t < 256) {
#pragma unroll
    for (int w2 = 0; w2 < 8; w2++) whist[w2][t] = 0;
    sbase[t] = gbase[t * nB + b];
  }
  __syncthreads();
  int w = t >> 6, lane = t & 63;
  u64 lowmask = (1ull << lane) - 1ull;
  u32 kk[16], vv[16], dig[16], rnk[16];
#pragma unroll
  for (int j = 0; j < 16; j++) {
    int idx = base + w * 1024 + j * 64 + lane;
    kk[j] = kin[idx];
    vv[j] = vin[idx];
  }
#pragma unroll
  for (int j = 0; j < 16; j++) {
    u32 d = (kk[j] >> shift) & 255u;
    u64 m = ~0ull;
#pragma unroll
    for (int bit = 0; bit < 8; bit++) {
      u64 bal = __ballot((d >> bit) & 1u);
      m &= ((d >> bit) & 1u) ? bal : ~bal;
    }
    u32 rr = (u32)__popcll(m & lowmask);
    u32 cnt = (u32)__popcll(m);
    u32 prev = whist[w][d];
    if (rr == 0) whist[w][d] = prev + cnt;
    dig[j] = d;
    rnk[j] = prev + rr;
  }
  __syncthreads();
  u32 tot = 0;
  if (t < 256) {
    u32 sacc = 0;
#pragma unroll
    for (int ww = 0; ww < 8; ww++) { u32 v = whist[ww][t]; whist[ww][t] = sacc; sacc += v; }
    tot = sacc;
    red[t] = tot;
  }
  __syncthreads();
  for (int off = 1; off < 256; off <<= 1) {
    u32 y = (t < 256 && t >= off) ? red[t - off] : 0u;
    __syncthreads();
    if (t < 256) red[t] += y;
    __syncthreads();
  }
  if (t < 256) {
    u32 lst = red[t] - tot;
    lstart[t] = lst;
    gdelta[t] = sbase[t] - lst;
  }
  __syncthreads();
#pragma unroll
  for (int j = 0; j < 16; j++) {
    u32 d = dig[j];
    u32 lpos = lstart[d] + whist[w][d] + rnk[j];
    sk[lpos] = kk[j];
    sv[lpos] = vv[j];
  }
  __syncthreads();
#pragma unroll
  for (int r = 0; r < 16; r++) {
    int idx = t + r * 512;
    u32 key = sk[idx];
    u32 d = (key >> shift) & 255u;
    u32 gpos = gdelta[d] + (u32)idx;
    u32 rv = sv[idx];
    int i = (int)(rv >> 9), jj = (int)(rv & 511);
    float A0 = (float)addr[(i << 10) + jj];
    float A1 = (float)addr[OFF1 + (i << 10) + jj];
    float A2 = (float)addr[OFF2 + (int)rv];
    ops[gpos] = make_float4(A0, A1, A2, 0.0f);
  }
}

// merged 3 convs: streaming 1->8ch 3x3 SAME on addr-as-float, relu,
// bf16x8 pack scattered directly to memory-position order featsM[addr[label]].
__global__ __launch_bounds__(256) void k_conv(const u32* __restrict__ addr,
                                              const float* __restrict__ cw0, const float* __restrict__ cb0,
                                              const float* __restrict__ cw1, const float* __restrict__ cb1,
                                              const float* __restrict__ cw2, const float* __restrict__ cb2,
                                              u16* __restrict__ featsM) {
  int b = blockIdx.x;
  int H, W, lw, off;
  const float *cw, *cb;
  int pix;
  if (b < 4096)      { H = 1024; W = 1024; lw = 10; off = 0;    cw = cw0; cb = cb0; pix = b * 256; }
  else if (b < 8192) { H = 1024; W = 1024; lw = 10; off = OFF1; cw = cw1; cb = cb1; pix = (b - 4096) * 256; }
  else               { H = 512;  W = 512;  lw = 9;  off = OFF2; cw = cw2; cb = cb2; pix = (b - 8192) * 256; }
  pix += threadIdx.x;
  int i = pix >> lw, j = pix & (W - 1);
  u32 m = addr[off + pix];  // destination memory position
  float x[3][3];
#pragma unroll
  for (int dr = 0; dr < 3; dr++)
#pragma unroll
    for (int dc = 0; dc < 3; dc++) {
      int r = i + dr - 1, c = j + dc - 1;
      bool inb = ((unsigned)r < (unsigned)H) && ((unsigned)c < (unsigned)W);
      x[dr][dc] = inb ? (float)addr[off + r * W + c] : 0.0f;
    }
  float acc[8];
#pragma unroll
  for (int oc = 0; oc < 8; oc++) {
    float s = cb[oc];
#pragma unroll
    for (int dr = 0; dr < 3; dr++)
#pragma unroll
      for (int dc = 0; dc < 3; dc++)
        s = fmaf(x[dr][dc], cw[oc * 9 + dr * 3 + dc], s);
    acc[oc] = fmaxf(s, 0.0f);
  }
  uint4 pk;
  pk.x = pk_bf16(acc[0], acc[1]);
  pk.y = pk_bf16(acc[2], acc[3]);
  pk.z = pk_bf16(acc[4], acc[5]);
  pk.w = pk_bf16(acc[6], acc[7]);
  *(uint4*)(featsM + (size_t)m * 8) = pk;
}

// 8->16ch 3x3 conv + fused 4x4 pool via MFMA 16x16x32 bf16.
// GEMM view: M = positions (row,lane), N = 16 oc, K = 72 (9 taps x 8 ic, padded to 96).
// A-fragment (lane holds row=lane&15, k-block=lane>>4): one tap x 8 ch = one 16B LDS read.
// B-fragment: wtbT[oc][k] bf16 -> one 16B global read per K-slice.
// C/D layout (verified): col = lane&15 (=oc), row = (lane>>4)*4 + reg.
__global__ __launch_bounds__(256) void k_memconv(const u16* __restrict__ featsM,
                                                 const u16* __restrict__ wtbT,
                                                 const float* __restrict__ mb,
                                                 float* __restrict__ partials) {
  __shared__ u16 tile[34 * 10 * 8];     // [row 0..33][lane-group 0..9 (halo 0,9)][ch 0..7]
  __shared__ float pool4[4][64];
  int t = threadIdx.x;
  int r0 = blockIdx.x * 32;
  // stage 34 rows x 8 groups (16B each), bf16 raw, into cols g=1..8
  for (int idx = t; idx < 34 * 8; idx += 256) {
    int rr = idx >> 3, g = idx & 7;
    int r = r0 - 1 + rr;
    uint4 u = make_uint4(0u, 0u, 0u, 0u);
    if ((unsigned)r < (unsigned)N_ROWS)
      u = *(const uint4*)(featsM + (size_t)(r * 8 + g) * 8);
    *(uint4*)(&tile[(rr * 10 + g + 1) * 8]) = u;
  }
  // halo zeros (g=0, g=9)
  for (int idx = t; idx < 34 * 2; idx += 256) {
    int rr = idx >> 1, side = idx & 1;
    *(uint4*)(&tile[(rr * 10 + side * 9) * 8]) = make_uint4(0u, 0u, 0u, 0u);
  }
  __syncthreads();
  int w = t >> 6, lane = t & 63;
  int hi = lane >> 4, lo = lane & 15;
  // B fragments: lane holds col n=lo, k = s*32 + hi*8 + j  (contiguous in wtbT[oc][k])
  short8 bfrag[3];
#pragma unroll
  for (int s = 0; s < 3; s++)
    bfrag[s] = *(const short8*)(wtbT + lo * 96 + s * 32 + hi * 8);
  // A-side per-lane tap for each K-slice: tap = s*4 + hi (taps 9..11 are zero pad)
  int dr_[3], dl_[3];
  bool valid_[3];
#pragma unroll
  for (int s = 0; s < 3; s++) {
    int tap = s * 4 + hi;
    valid_[s] = (tap < 9);
    int tp = valid_[s] ? tap : 0;
    dr_[s] = tp / 3;
    dl_[s] = tp % 3;
  }
  float bias = mb[lo];
  int pl = lo & 7;             // A-side lane col
  int prow_lo = lo >> 3;       // A-side row parity
  float S0 = 0.0f, S1 = 0.0f;  // pooled sums for this lane's two lane-blocks
#pragma unroll
  for (int tt = 0; tt < 4; tt++) {
    int prow = w * 8 + tt * 2 + prow_lo;   // A-side: position q = tt*16 + lo
    f32x4 acc = {0.0f, 0.0f, 0.0f, 0.0f};
#pragma unroll
    for (int s = 0; s < 3; s++) {
      short8 a = {0, 0, 0, 0, 0, 0, 0, 0};
      if (valid_[s])
        a = *(const short8*)(&tile[((prow + dr_[s]) * 10 + pl + dl_[s]) * 8]);
      acc = __builtin_amdgcn_mfma_f32_16x16x32_bf16(a, bfrag[s], acc, 0, 0, 0);
    }
    // D-side: lane holds rows m = hi*4+reg, col oc=lo ->
    // position q = tt*16 + hi*4 + reg; pl_D = (hi&1)*4 + reg; lb = (hi&1)*2 + (reg>>1)
    float v0 = fmaxf(acc[0] + bias, 0.0f);
    float v1 = fmaxf(acc[1] + bias, 0.0f);
    float v2 = fmaxf(acc[2] + bias, 0.0f);
    float v3 = fmaxf(acc[3] + bias, 0.0f);
    S0 += v0 + v1;   // lb = (hi&1)*2
    S1 += v2 + v3;   // lb = (hi&1)*2 + 1
  }
  // combine lanes hi and hi^2 (same oc, same lb pair)
  S0 += __shfl_xor(S0, 32, 64);
  S1 += __shfl_xor(S1, 32, 64);
  if (hi < 2) {
    int lb0 = (hi & 1) * 2;
    pool4[w][lo * 4 + lb0]     = S0;
    pool4[w][lo * 4 + lb0 + 1] = S1;
  }
  __syncthreads();
  if (t < 64) {
    float s = pool4[0][t] + pool4[1][t] + pool4[2][t] + pool4[3][t];
    partials[(size_t)t * 9216 + blockIdx.x] = s;   // t = oc*4 + lb
  }
}

__global__ __launch_bounds__(256) void k_pool_final(const float* __restrict__ partials,
                                                    float* __restrict__ flat) {
  int f = blockIdx.x;
  int oc = f >> 4, rb = (f >> 2) & 3, lb = f & 3;
  const float* src = partials + (size_t)(oc * 4 + lb) * 9216 + rb * 2304;
  double s = 0.0;
  for (int i = threadIdx.x; i < 2304; i += 256) s += (double)src[i];
  __shared__ double sd[256];
  sd[threadIdx.x] = s;
  __syncthreads();
  for (int off = 128; off > 0; off >>= 1) {
    if (threadIdx.x < off) sd[threadIdx.x] += sd[threadIdx.x + off];
    __syncthreads();
  }
  if (threadIdx.x == 0) flat[f] = (float)(sd[0] * (1.0 / 147456.0));
}

// one wave per 32 rows of proj_w; also emits sort2 keys+vals
__global__ __launch_bounds__(256) void k_matvec(const float* __restrict__ pw,
                                                const float* __restrict__ pb,
                                                const float* __restrict__ flat,
                                                float* __restrict__ out,
                                                u32* __restrict__ k2, u32* __restrict__ v2) {
  int t = threadIdx.x;
  int lane = t & 63;
  int g = (blockIdx.x * 256 + t) >> 6;
  float4 f4 = ((const float4*)flat)[lane];
  int row0 = g * 32;
  for (int it = 0; it < 32; it += 2) {
    int row = row0 + it;
    float4 wa = ((const float4*)(pw + (size_t)row * 256))[lane];
    float4 wb = ((const float4*)(pw + (size_t)(row + 1) * 256))[lane];
    float sa = wa.x * f4.x + wa.y * f4.y + wa.z * f4.z + wa.w * f4.w;
    float sb = wb.x * f4.x + wb.y * f4.y + wb.z * f4.z + wb.w * f4.w;
#pragma unroll
    for (int off = 32; off > 0; off >>= 1) {
      sa += __shfl_xor(sa, off, 64);
      sb += __shfl_xor(sb, off, 64);
    }
    if (lane == 0) {
      float ra = sa + pb[row], rb2 = sb + pb[row + 1];
      out[row] = ra;
      out[row + 1] = rb2;
      u32 ua = __float_as_uint(ra), ub = __float_as_uint(rb2);
      ua = (ua & 0x80000000u) ? ~ua : (ua | 0x80000000u);
      ub = (ub & 0x80000000u) ? ~ub : (ub | 0x80000000u);
      k2[row] = ua; k2[row + 1] = ub;
      v2[row] = (u32)row; v2[row + 1] = (u32)(row + 1);
    }
  }
}

__device__ inline double staged_pair(float x) {
  float h = fabsf(x);
  double mult = (h <= 2.f) ? 1.0 : (h <= 4.f) ? 1.5 : (h <= 8.f) ? 2.0 : (h <= 16.f) ? 3.0 : 5.0;
  double hh = (double)h;
  if (x > 0.f) return hh * mult;
  if (x < 0.f) return hh * hh * mult;
  return 0.0;
}

__global__ __launch_bounds__(256) void k_penalty(const float4* __restrict__ ops,
                                                 double* __restrict__ ppart) {
  int k = blockIdx.x * 256 + threadIdx.x;
  float4 a = ops[k];
  double intra = staged_pair(a.y - a.x) + staged_pair(a.z - a.y);
  double inter = 0.0;
  if (k < N_OPS - 1) {
    float4 b = ops[k + 1];
    inter = staged_pair(b.x - a.z);
  }
  __shared__ double s0[256], s1[256];
  s0[threadIdx.x] = inter;
  s1[threadIdx.x] = intra;
  __syncthreads();
  for (int off = 128; off > 0; off >>= 1) {
    if (threadIdx.x < off) {
      s0[threadIdx.x] += s0[threadIdx.x + off];
      s1[threadIdx.x] += s1[threadIdx.x + off];
    }
    __syncthreads();
  }
  if (threadIdx.x == 0) {
    ppart[blockIdx.x] = s0[0];
    ppart[1024 + blockIdx.x] = s1[0];
  }
}

__global__ __launch_bounds__(256) void k_finalize(const double* __restrict__ ppart,
                                                  float* __restrict__ out) {
  int t = threadIdx.x;
  double s0 = 0.0, s1 = 0.0;
  for (int i = t; i < 1024; i += 256) {
    s0 += ppart[i];
    s1 += ppart[1024 + i];
  }
  __shared__ double a0[256], a1[256];
  a0[t] = s0;
  a1[t] = s1;
  __syncthreads();
  for (int off = 128; off > 0; off >>= 1) {
    if (t < off) {
      a0[t] += a0[t + off];
      a1[t] += a1[t + off];
    }
    __syncthreads();
  }
  if (t == 0) {
    out[N_OPS] = (float)a0[0];
    out[N_OPS + 1] = (float)a1[0];
  }
}

extern "C" void kernel_launch(void* const* d_in, const int* in_sizes, int n_in,
                              void* d_out, int out_size, void* d_ws, size_t ws_size,
                              hipStream_t stream) {
  const float* mem_logits = (const float*)d_in[0];
  const float* cw0 = (const float*)d_in[1];
  const float* cb0 = (const float*)d_in[2];
  const float* cw1 = (const float*)d_in[3];
  const float* cb1 = (const float*)d_in[4];
  const float* cw2 = (const float*)d_in[5];
  const float* cb2 = (const float*)d_in[6];
  const float* mw  = (const float*)d_in[7];
  const float* mbb = (const float*)d_in[8];
  const float* pw  = (const float*)d_in[9];
  const float* pb  = (const float*)d_in[10];
  float* out = (float*)d_out;
  char* ws = (char*)d_ws;

  u32* addr      = (u32*)(ws);
  u16* featsM    = (u16*)(ws + OFF_F8);
  u32* kA        = (u32*)(ws + OFF_F8);
  u32* kB        = (u32*)(ws + OFF_F8 + 9437184ull);
  u32* v0        = (u32*)(ws + OFF_F8 + 18874368ull);
  u32* v1        = (u32*)(ws + OFF_F8 + 28311552ull);
  u32* counts    = (u32*)(ws + OFF_COUNTS);
  u32* pos       = (u32*)(ws + OFF_POS);
  float* partials= (float*)(ws + OFF_PART);
  float* flat    = (float*)(ws + OFF_FLAT);
  u16* wtbT      = (u16*)(ws + OFF_WT);
  double* ppart  = (double*)(ws + OFF_PPART);
  float4* ops    = (float4*)(ws + OFF_OPS);
  u32* k2A       = (u32*)(ws + OFF_S2);
  u32* k2B       = (u32*)(ws + OFF_S2 + 1048576ull);
  u32* v2A       = (u32*)(ws + OFF_S2 + 2097152ull);
  u32* v2B       = (u32*)(ws + OFF_S2 + 3145728ull);

  // ---- sort1: keys + pass-0 hist fused in k_front; passes 1,2 use k_hist ----
  k_front<<<289, 256, 0, stream>>>(mem_logits, kA, counts, mw, wtbT);
  k_scan_par<<<256, 256, 0, stream>>>(counts, pos, 288);
  k_scatter<<<288, 512, 0, stream>>>(kA, nullptr, kB, v0, pos, 8, 288, 1, 0);
  k_hist<<<288, 512, 0, stream>>>(kB, counts, 16, 288);
  k_scan_par<<<256, 256, 0, stream>>>(counts, pos, 288);
  k_scatter<<<288, 512, 0, stream>>>(kB, v0, kA, v1, pos, 16, 288, 0, 0);
  k_hist<<<288, 512, 0, stream>>>(kA, counts, 24, 288);
  k_scan_par<<<256, 256, 0, stream>>>(counts, pos, 288);
  k_scatter<<<288, 512, 0, stream>>>(kA, v1, nullptr, addr, pos, 24, 288, 0, 1);

  // ---- streaming convs (scatter to memory order), MFMA memconv + pool ----
  k_conv<<<9216, 256, 0, stream>>>(addr, cw0, cb0, cw1, cb1, cw2, cb2, featsM);
  k_memconv<<<9216, 256, 0, stream>>>(featsM, wtbT, mbb, partials);
  k_pool_final<<<256, 256, 0, stream>>>(partials, flat);

  // ---- projection matvec -> op_logits + sort2 keys ----
  k_matvec<<<2048, 256, 0, stream>>>(pw, pb, flat, out, k2A, v2A);

  // ---- sort2: 3 passes over bits [8..32); final pass emits A-table ----
  k_hist<<<32, 512, 0, stream>>>(k2A, counts, 8, 32);
  k_scan_par<<<256, 256, 0, stream>>>(counts, pos, 32);
  k_scatter<<<32, 512, 0, stream>>>(k2A, v2A, k2B, v2B, pos, 8, 32, 0, 0);
  k_hist<<<32, 512, 0, stream>>>(k2B, counts, 16, 32);
  k_scan_par<<<256, 256, 0, stream>>>(counts, pos, 32);
  k_scatter<<<32, 512, 0, stream>>>(k2B, v2B, k2A, v2A, pos, 16, 32, 0, 0);
  k_hist<<<32, 512, 0, stream>>>(k2A, counts, 24, 32);
  k_scan_par<<<256, 256, 0, stream>>>(counts, pos, 32);
  k_scatter_ops<<<32, 512, 0, stream>>>(k2A, v2A, pos, 24, 32, addr, ops);

  // ---- penalties (split two-kernel reduction, no global atomics) ----
  k_penalty<<<1024, 256, 0, stream>>>(ops, ppart);
  k_finalize<<<1, 256, 0, stream>>>(ppart, out);
}